// Round 2
// baseline (650.032 us; speedup 1.0000x reference)
//
#include <hip/hip_runtime.h>
#include <hip/hip_fp16.h>

// MultiHeadSelfAttention fwd: B=8, N=1024, E=768, H=12, D=64.
// cast x->f16 | transpose-cast weights | qkv GEMM (MFMA f16, V written
// transposed) | fused attn (S=QK^T f16 in 64KB LDS, in-reg softmax, attn
// written from regs, P re-packed to swizzled fragment blocks, PV) | proj GEMM.
// Roofline: attn write 402MB dominates -> ~74us memory floor.

typedef _Float16 f16x8 __attribute__((ext_vector_type(8)));
typedef _Float16 f16x4 __attribute__((ext_vector_type(4)));
typedef float f32x4 __attribute__((ext_vector_type(4)));

#define B_ 8
#define N_ 1024
#define E_ 768
#define H_ 12
#define D_ 64

// ---------------- cast x (fp32 -> f16), vectorized ----------------
__global__ __launch_bounds__(256) void cast_x_kernel(const float* __restrict__ in,
                                                     _Float16* __restrict__ out, int n4) {
  int stride = gridDim.x * blockDim.x;
  for (int i = blockIdx.x * blockDim.x + threadIdx.x; i < n4; i += stride) {
    float4 v = reinterpret_cast<const float4*>(in)[i];
    f16x4 o = { (_Float16)v.x, (_Float16)v.y, (_Float16)v.z, (_Float16)v.w };
    reinterpret_cast<f16x4*>(out)[i] = o;
  }
}

// ---------------- transpose + cast (fp32 [rows][cols] -> f16 [cols][rows]) ----------------
__global__ __launch_bounds__(256) void transpose_cast_kernel(const float* __restrict__ in,
                                                             _Float16* __restrict__ out,
                                                             int rows, int cols) {
  __shared__ float tile[32][33];
  int c0 = blockIdx.x * 32, r0 = blockIdx.y * 32;
  int tx = threadIdx.x & 31, ty = threadIdx.x >> 5;  // 32 x 8
  #pragma unroll
  for (int i = 0; i < 32; i += 8)
    tile[ty + i][tx] = in[(size_t)(r0 + ty + i) * cols + c0 + tx];
  __syncthreads();
  #pragma unroll
  for (int i = 0; i < 32; i += 8)
    out[(size_t)(c0 + ty + i) * rows + r0 + tx] = (_Float16)tile[tx][ty + i];
}

// ---------------- qkv GEMM: [8192x768] f16 x [2304x768]^T f16 -> q,k [B,H,N,D]; v TRANSPOSED [B,H,D,N] ----------------
// m97 structure: 128x128 tile, BK=32, 4 waves (2x2), 4x4 16x16x32 frags/wave,
// global_load_lds width=16 staging, single LDS buffer, 2 barriers/K-step.
__global__ __launch_bounds__(256) void gemm_qkv_kernel(const _Float16* __restrict__ A,
                                                       const _Float16* __restrict__ Bt,
                                                       _Float16* __restrict__ q,
                                                       _Float16* __restrict__ k,
                                                       _Float16* __restrict__ vt) {
  __shared__ _Float16 As[128 * 32];
  __shared__ _Float16 Bs[128 * 32];
  const int tid = threadIdx.x, lane = tid & 63, w = tid >> 6;
  const int wr = w >> 1, wc = w & 1;
  const int m0 = blockIdx.y * 128, n0 = blockIdx.x * 128;
  const f32x4 zero = {0.f, 0.f, 0.f, 0.f};
  f32x4 acc[4][4];
  #pragma unroll
  for (int m = 0; m < 4; m++)
    #pragma unroll
    for (int n = 0; n < 4; n++) acc[m][n] = zero;
  const int srow = lane >> 2;        // 0..15 within 16-row chunk
  const int skof = (lane & 3) * 8;   // k offset 0/8/16/24
  for (int k0 = 0; k0 < 768; k0 += 32) {
    #pragma unroll
    for (int i = 0; i < 2; i++) {
      int c = w * 2 + i;             // 1KB chunk id, 0..7
      int row = c * 16 + srow;
      const _Float16* ga = A + (size_t)(m0 + row) * 768 + k0 + skof;
      __builtin_amdgcn_global_load_lds((const __attribute__((address_space(1))) void*)ga,
                                       (__attribute__((address_space(3))) void*)(As + c * 512),
                                       16, 0, 0);
      const _Float16* gb = Bt + (size_t)(n0 + row) * 768 + k0 + skof;
      __builtin_amdgcn_global_load_lds((const __attribute__((address_space(1))) void*)gb,
                                       (__attribute__((address_space(3))) void*)(Bs + c * 512),
                                       16, 0, 0);
    }
    __syncthreads();
    f16x8 af[4], bfr[4];
    #pragma unroll
    for (int m = 0; m < 4; m++)
      af[m] = *reinterpret_cast<const f16x8*>(&As[(wr * 64 + m * 16 + (lane & 15)) * 32 + (lane >> 4) * 8]);
    #pragma unroll
    for (int n = 0; n < 4; n++)
      bfr[n] = *reinterpret_cast<const f16x8*>(&Bs[(wc * 64 + n * 16 + (lane & 15)) * 32 + (lane >> 4) * 8]);
    #pragma unroll
    for (int m = 0; m < 4; m++)
      #pragma unroll
      for (int n = 0; n < 4; n++)
        acc[m][n] = __builtin_amdgcn_mfma_f32_16x16x32_f16(af[m], bfr[n], acc[m][n], 0, 0, 0);
    __syncthreads();
  }
  // epilogue: C/D layout col=lane&15, row=4*(lane>>4)+j (m89-verified)
  const int g = lane >> 4, cc = lane & 15;
  #pragma unroll
  for (int n = 0; n < 4; n++) {
    int C = n0 + wc * 64 + n * 16 + cc;
    int mat = C / 768;
    int e = C - mat * 768;
    int h = e >> 6, d = e & 63;
    #pragma unroll
    for (int m = 0; m < 4; m++) {
      int R0 = m0 + wr * 64 + m * 16 + 4 * g;     // 4-aligned, never crosses b
      int b = R0 >> 10, nn0 = R0 & 1023;
      if (mat == 2) {
        // v transposed: [bh][d][n], 4 consecutive n -> one 8B store
        f16x4 pk = { (_Float16)acc[m][n][0], (_Float16)acc[m][n][1],
                     (_Float16)acc[m][n][2], (_Float16)acc[m][n][3] };
        *reinterpret_cast<f16x4*>(&vt[(((size_t)b * H_ + h) * D_ + d) * N_ + nn0]) = pk;
      } else {
        _Float16* dst = (mat == 0) ? q : k;
        #pragma unroll
        for (int j = 0; j < 4; j++)
          dst[(((size_t)b * H_ + h) * N_ + nn0 + j) * D_ + d] = (_Float16)acc[m][n][j];
      }
    }
  }
}

// ---------------- fused attention: per (bh, 32-row Q tile), 8 waves, 64KB LDS ----------------
// A: S=QK^T*scale (f16, row-major [32][1024])
// B: in-register softmax (row in 32 VGPRs), attn written from regs (fp32, normalized)
// P re-packed in-place into swizzled 16B fragment blocks: blk = kc*32 + (row ^ (2kc&31))
// D: PV from P-blocks (conflict-free) x Vt (f16x8 loads) -> pv f16 [B,N,E]
__global__ __launch_bounds__(512, 4) void attn_kernel(const _Float16* __restrict__ Q,
                                                      const _Float16* __restrict__ K,
                                                      const _Float16* __restrict__ Vt,
                                                      float* __restrict__ attn_out,
                                                      _Float16* __restrict__ pv) {
  __shared__ __align__(16) _Float16 S[32 * 1024];  // 64KB: scores, then P-blocks (in-place)
  const int bh = blockIdx.y;       // 0..95 = b*H+h
  const int qbase = blockIdx.x * 32;
  const int tid = threadIdx.x, lane = tid & 63, w = tid >> 6;
  const int g = lane >> 4, cc = lane & 15;
  const _Float16* Qp = Q + ((size_t)bh * N_ + qbase) * D_;
  const _Float16* Kp = K + (size_t)bh * N_ * D_;
  const _Float16* Vp = Vt + (size_t)bh * D_ * N_;
  const float scale = 0.125f;  // D^-0.5
  const f32x4 zero = {0.f, 0.f, 0.f, 0.f};

  // ---- phase A: scores. wave w owns key col-tiles w, w+8, ..., w+56 ----
  f16x8 aq[2][2];
  #pragma unroll
  for (int rt = 0; rt < 2; rt++)
    #pragma unroll
    for (int ks = 0; ks < 2; ks++)
      aq[rt][ks] = *reinterpret_cast<const f16x8*>(Qp + (size_t)(rt * 16 + cc) * D_ + ks * 32 + g * 8);
  for (int ct = w; ct < 64; ct += 8) {
    f16x8 kb[2];
    #pragma unroll
    for (int ks = 0; ks < 2; ks++)
      kb[ks] = *reinterpret_cast<const f16x8*>(Kp + (size_t)(ct * 16 + cc) * D_ + ks * 32 + g * 8);
    #pragma unroll
    for (int rt = 0; rt < 2; rt++) {
      f32x4 s = zero;
      s = __builtin_amdgcn_mfma_f32_16x16x32_f16(aq[rt][0], kb[0], s, 0, 0, 0);
      s = __builtin_amdgcn_mfma_f32_16x16x32_f16(aq[rt][1], kb[1], s, 0, 0, 0);
      #pragma unroll
      for (int j = 0; j < 4; j++)
        S[(rt * 16 + 4 * g + j) * 1024 + ct * 16 + cc] = (_Float16)(s[j] * scale);
    }
  }
  __syncthreads();

  // ---- phase B: softmax. wave w, g-group -> row r = w*4+g; 16 lanes x 8 x f16x8 = full row ----
  const int r = w * 4 + g;
  f16x8 sreg[8];
  float mx = -3.0e38f;
  #pragma unroll
  for (int i = 0; i < 8; i++) {
    sreg[i] = *reinterpret_cast<const f16x8*>(&S[r * 1024 + cc * 8 + 128 * i]);
    #pragma unroll
    for (int j = 0; j < 8; j++) mx = fmaxf(mx, (float)sreg[i][j]);
  }
  #pragma unroll
  for (int m = 1; m < 16; m <<= 1) mx = fmaxf(mx, __shfl_xor(mx, m));
  float sum = 0.f;
  #pragma unroll
  for (int i = 0; i < 8; i++) {
    #pragma unroll
    for (int j = 0; j < 8; j++) {
      float p = __expf((float)sreg[i][j] - mx);
      sum += p;
      sreg[i][j] = (_Float16)p;
    }
  }
  #pragma unroll
  for (int m = 1; m < 16; m <<= 1) sum += __shfl_xor(sum, m);
  const float iv = 1.f / sum;

  // attn written straight from regs (fp32, normalized); repack sreg = p*iv (f16)
  float* Ao = attn_out + ((size_t)bh * N_ + qbase + r) * N_;
  #pragma unroll
  for (int i = 0; i < 8; i++) {
    float pn[8];
    #pragma unroll
    for (int j = 0; j < 8; j++) {
      pn[j] = (float)sreg[i][j] * iv;
      sreg[i][j] = (_Float16)pn[j];
    }
    float4 o0 = {pn[0], pn[1], pn[2], pn[3]};
    float4 o1 = {pn[4], pn[5], pn[6], pn[7]};
    reinterpret_cast<float4*>(Ao + cc * 8 + 128 * i)[0] = o0;
    reinterpret_cast<float4*>(Ao + cc * 8 + 128 * i + 4)[0] = o1;
  }
  __syncthreads();  // all S reads done -> safe to overwrite in-place

  // P-blocks: 16B block (kc=col/8, row) at blk = kc*32 + (row ^ (2kc&31))
  #pragma unroll
  for (int i = 0; i < 8; i++) {
    int kc = cc + 16 * i;
    int blk = kc * 32 + (r ^ ((2 * kc) & 31));
    *reinterpret_cast<f16x8*>(&S[blk * 8]) = sreg[i];
  }
  __syncthreads();

  // ---- phase D: PV. wave w -> row-tile rt=w>>2, d-tile dt=w&3 ----
  const int rt = w >> 2, dt = w & 3;
  const _Float16* vrow = Vp + (size_t)(dt * 16 + cc) * N_;
  f32x4 acc = zero;
  #pragma unroll 2
  for (int k0 = 0; k0 < N_; k0 += 32) {
    int kc = (k0 >> 3) + g;
    int blk = kc * 32 + ((rt * 16 + cc) ^ ((2 * kc) & 31));
    f16x8 pa = *reinterpret_cast<const f16x8*>(&S[blk * 8]);
    f16x8 vb = *reinterpret_cast<const f16x8*>(vrow + k0 + g * 8);
    acc = __builtin_amdgcn_mfma_f32_16x16x32_f16(pa, vb, acc, 0, 0, 0);
  }
  const int b = bh / H_, h = bh - b * H_;
  #pragma unroll
  for (int j = 0; j < 4; j++) {
    int n = qbase + rt * 16 + 4 * g + j;
    pv[((size_t)b * N_ + n) * E_ + h * 64 + dt * 16 + cc] = (_Float16)acc[j];
  }
}

// ---------------- proj GEMM: pv [8192x768] f16 x w_projT [768x768] f16 + bias -> out fp32 ----------------
__global__ __launch_bounds__(256) void gemm_proj_kernel(const _Float16* __restrict__ A,
                                                        const _Float16* __restrict__ Bt,
                                                        const float* __restrict__ bias,
                                                        float* __restrict__ out) {
  __shared__ _Float16 As[128 * 32];
  __shared__ _Float16 Bs[128 * 32];
  const int tid = threadIdx.x, lane = tid & 63, w = tid >> 6;
  const int wr = w >> 1, wc = w & 1;
  const int m0 = blockIdx.y * 128, n0 = blockIdx.x * 128;
  const f32x4 zero = {0.f, 0.f, 0.f, 0.f};
  f32x4 acc[4][4];
  #pragma unroll
  for (int m = 0; m < 4; m++)
    #pragma unroll
    for (int n = 0; n < 4; n++) acc[m][n] = zero;
  const int srow = lane >> 2;
  const int skof = (lane & 3) * 8;
  for (int k0 = 0; k0 < 768; k0 += 32) {
    #pragma unroll
    for (int i = 0; i < 2; i++) {
      int c = w * 2 + i;
      int row = c * 16 + srow;
      const _Float16* ga = A + (size_t)(m0 + row) * 768 + k0 + skof;
      __builtin_amdgcn_global_load_lds((const __attribute__((address_space(1))) void*)ga,
                                       (__attribute__((address_space(3))) void*)(As + c * 512),
                                       16, 0, 0);
      const _Float16* gb = Bt + (size_t)(n0 + row) * 768 + k0 + skof;
      __builtin_amdgcn_global_load_lds((const __attribute__((address_space(1))) void*)gb,
                                       (__attribute__((address_space(3))) void*)(Bs + c * 512),
                                       16, 0, 0);
    }
    __syncthreads();
    f16x8 af[4], bfr[4];
    #pragma unroll
    for (int m = 0; m < 4; m++)
      af[m] = *reinterpret_cast<const f16x8*>(&As[(wr * 64 + m * 16 + (lane & 15)) * 32 + (lane >> 4) * 8]);
    #pragma unroll
    for (int n = 0; n < 4; n++)
      bfr[n] = *reinterpret_cast<const f16x8*>(&Bs[(wc * 64 + n * 16 + (lane & 15)) * 32 + (lane >> 4) * 8]);
    #pragma unroll
    for (int m = 0; m < 4; m++)
      #pragma unroll
      for (int n = 0; n < 4; n++)
        acc[m][n] = __builtin_amdgcn_mfma_f32_16x16x32_f16(af[m], bfr[n], acc[m][n], 0, 0, 0);
    __syncthreads();
  }
  const int g = lane >> 4, cc = lane & 15;
  #pragma unroll
  for (int n = 0; n < 4; n++) {
    int C = n0 + wc * 64 + n * 16 + cc;
    float bb = bias[C];
    #pragma unroll
    for (int m = 0; m < 4; m++) {
      #pragma unroll
      for (int j = 0; j < 4; j++) {
        int R = m0 + wr * 64 + m * 16 + 4 * g + j;
        out[(size_t)R * 768 + C] = acc[m][n][j] + bb;
      }
    }
  }
}

extern "C" void kernel_launch(void* const* d_in, const int* in_sizes, int n_in,
                              void* d_out, int out_size, void* d_ws, size_t ws_size,
                              hipStream_t stream) {
  const float* x      = (const float*)d_in[0];
  const float* w_qkv  = (const float*)d_in[1];
  const float* w_proj = (const float*)d_in[2];
  const float* b_proj = (const float*)d_in[3];
  float* out  = (float*)d_out;
  float* attn = out + (size_t)B_ * N_ * E_;  // tuple: (out, attn) concat

  char* ws = (char*)d_ws;
  const size_t SZ_XH    = (size_t)B_ * N_ * E_ * 2;       // 12,582,912
  const size_t SZ_WQKVT = (size_t)E_ * 3 * E_ * 2;        //  3,538,944
  const size_t SZ_WPROJT= (size_t)E_ * E_ * 2;            //  1,179,648
  _Float16* xh     = (_Float16*)(ws);
  _Float16* wqkvT  = (_Float16*)(ws + SZ_XH);
  _Float16* wprojT = (_Float16*)(ws + SZ_XH + SZ_WQKVT);
  _Float16* qh     = (_Float16*)(ws + SZ_XH + SZ_WQKVT + SZ_WPROJT);
  _Float16* kh     = qh + (size_t)B_ * H_ * N_ * D_;
  _Float16* vth    = kh + (size_t)B_ * H_ * N_ * D_;
  _Float16* pvh    = vth + (size_t)B_ * H_ * N_ * D_;

  cast_x_kernel<<<dim3(2048), dim3(256), 0, stream>>>(x, xh, (B_ * N_ * E_) / 4);
  transpose_cast_kernel<<<dim3(3 * E_ / 32, E_ / 32), dim3(256), 0, stream>>>(w_qkv, wqkvT, E_, 3 * E_);
  transpose_cast_kernel<<<dim3(E_ / 32, E_ / 32), dim3(256), 0, stream>>>(w_proj, wprojT, E_, E_);
  gemm_qkv_kernel<<<dim3(3 * E_ / 128, B_ * N_ / 128), dim3(256), 0, stream>>>(xh, wqkvT, qh, kh, vth);
  attn_kernel<<<dim3(N_ / 32, B_ * H_), dim3(512), 0, stream>>>(qh, kh, vth, attn, pvh);
  gemm_proj_kernel<<<dim3(E_ / 128, B_ * N_ / 128), dim3(256), 0, stream>>>(pvh, wprojT, b_proj, out);
}